// Round 16
// baseline (120.057 us; speedup 1.0000x reference)
//
#include <hip/hip_runtime.h>
#include <hip/hip_bf16.h>
#include <stdint.h>
#include <stddef.h>

#define TT 4096
#define CC 1024
#define NFD 1024
#define N3 3072
// k_pvc 4-way split-K fixed j-tile boundaries: [0,9) [9,17) [17,25) [25,32)
#define PB0 1152   // first row using part0/part1 (it>=9)
#define PB2 2176   // first row using part2 (it>=17)

typedef __bf16 bf16;
typedef __bf16 bf16x8 __attribute__((ext_vector_type(8)));
typedef __bf16 bf16x4 __attribute__((ext_vector_type(4)));
typedef float f32x4 __attribute__((ext_vector_type(4)));

typedef const __attribute__((address_space(1))) unsigned char gl_u8;
typedef __attribute__((address_space(3))) unsigned char lds_u8;

__device__ __forceinline__ void glds16(const void* g, void* l) {
  __builtin_amdgcn_global_load_lds((gl_u8*)g, (lds_u8*)l, 16, 0, 0);
}

// Stage a 128x32 bf16 tile (row-major, ld in elements) into linear LDS [128][32].
__device__ __forceinline__ void stage128x32(const bf16* __restrict__ src, int ld, bf16* lds, int tid) {
  const int lane = tid & 63;
  const int w = tid >> 6;
#pragma unroll
  for (int p = 0; p < 2; ++p) {
    const int lbyte = w * 2048 + p * 1024;              // wave-uniform LDS base (bytes)
    const int row = (lbyte >> 6) + (lane >> 2);         // this lane's 16B lands at row, k8
    const int kel = (lane & 3) << 3;
    glds16(src + row * ld + kel, (char*)lds + lbyte);
  }
}

// ---------- R6 core (best measured across 6 pipeline experiments):
// 128x128, BK=32, 2-buffer, 1 barrier/step. ----------
__device__ __forceinline__ void gemm_core(const bf16* __restrict__ A, const bf16* __restrict__ B,
                                          int lda, int ldb, int ksteps,
                                          bf16* As, bf16* Bs, int tid, f32x4 (&acc)[4][4]) {
  const int lane = tid & 63;
  const int w = tid >> 6;
  const int wm = (w >> 1) * 64;
  const int wn = (w & 1) * 64;
  const int lrow = lane & 15;
  const int lko = (lane >> 4) * 8;
  stage128x32(A, lda, As, tid);
  stage128x32(B, ldb, Bs, tid);
  __syncthreads();
  for (int ks = 0; ks < ksteps; ++ks) {
    const bf16* Ac = As + (ks & 1) * 4096;
    const bf16* Bc = Bs + (ks & 1) * 4096;
    if (ks + 1 < ksteps) {
      stage128x32(A + (ks + 1) * 32, lda, As + ((ks + 1) & 1) * 4096, tid);
      stage128x32(B + (ks + 1) * 32, ldb, Bs + ((ks + 1) & 1) * 4096, tid);
    }
    bf16x8 af[4], bfr[4];
#pragma unroll
    for (int i = 0; i < 4; ++i)
      af[i] = *(const bf16x8*)(Ac + (wm + i * 16 + lrow) * 32 + lko);
#pragma unroll
    for (int i = 0; i < 4; ++i)
      bfr[i] = *(const bf16x8*)(Bc + (wn + i * 16 + lrow) * 32 + lko);
#pragma unroll
    for (int mi = 0; mi < 4; ++mi)
#pragma unroll
      for (int ni = 0; ni < 4; ++ni)
        acc[mi][ni] = __builtin_amdgcn_mfma_f32_16x16x32_bf16(af[mi], bfr[ni], acc[mi][ni], 0, 0, 0);
    __syncthreads();
  }
}

// ---- K0: merged prep. [0,2048): x cvt. [2048,2816): W transpose. 2816: zero l. ----
__global__ __launch_bounds__(256) void k_prep(const float* __restrict__ x, bf16* __restrict__ xb,
                                              const float* __restrict__ Wsrc, bf16* __restrict__ WbT,
                                              float* __restrict__ l) {
  __shared__ float Ls[64][65];
  const int tid = threadIdx.x;
  if (blockIdx.x < 2048) {
    int idx = (blockIdx.x * 256 + tid) * 8;
    f32x4 a = *(const f32x4*)(x + idx);
    f32x4 b = *(const f32x4*)(x + idx + 4);
    bf16x8 o;
#pragma unroll
    for (int j = 0; j < 4; ++j) { o[j] = (bf16)a[j]; o[4 + j] = (bf16)b[j]; }
    *(bf16x8*)(xb + idx) = o;
    return;
  }
  if (blockIdx.x == 2048 + 768) {  // zero the l accumulator (TT floats)
    f32x4 z = (f32x4){0.f, 0.f, 0.f, 0.f};
#pragma unroll
    for (int qq = 0; qq < 4; ++qq)
      *(f32x4*)(l + (qq * 256 + tid) * 4) = z;
    return;
  }
  const int bid = blockIdx.x - 2048;
  const int n0 = (bid % 48) * 64;
  const int c0 = (bid / 48) * 64;
#pragma unroll
  for (int qq = 0; qq < 4; ++qq) {
    int lin = qq * 1024 + tid * 4;
    int r = lin >> 6, cc = lin & 63;
    f32x4 v = *(const f32x4*)(Wsrc + (size_t)(c0 + r) * N3 + n0 + cc);
#pragma unroll
    for (int j = 0; j < 4; ++j) Ls[r][cc + j] = v[j];
  }
  __syncthreads();
#pragma unroll
  for (int qq = 0; qq < 4; ++qq) {
    int lin = qq * 1024 + tid * 4;
    int nr = lin >> 6, cc = lin & 63;
    bf16x4 o;
#pragma unroll
    for (int j = 0; j < 4; ++j) o[j] = (bf16)Ls[cc + j][nr];
    *(bf16x4*)(WbT + (size_t)(n0 + nr) * CC + c0 + cc) = o;
  }
}

// ---- K1: q,k projection only (jt 0..15). 1D XCD-chunked: XCD r owns 4 it x 16 jt. ----
__global__ __launch_bounds__(256, 2) void k_qkv_qk(const bf16* __restrict__ xb, const bf16* __restrict__ wbt,
                                                   const float* __restrict__ bias,
                                                   bf16* __restrict__ q, bf16* __restrict__ k) {
  __shared__ bf16 As[2 * 128 * 32], Bs[2 * 128 * 32];
  const int tid = threadIdx.x;
  const int id = blockIdx.x;         // 0..511
  const int r = id & 7;              // XCD (round-robin heuristic, m09)
  const int s = id >> 3;             // 0..63 within XCD
  const int it = 4 * r + (s & 3);    // 0..31
  const int jt = s >> 2;             // 0..15
  const int m0 = it * 128;
  const int n0 = jt * 128;
  f32x4 acc[4][4];
#pragma unroll
  for (int i = 0; i < 4; ++i)
#pragma unroll
    for (int j = 0; j < 4; ++j) acc[i][j] = (f32x4){0.f, 0.f, 0.f, 0.f};

  gemm_core(xb + (size_t)m0 * CC, wbt + (size_t)n0 * CC, CC, CC, CC / 32, As, Bs, tid, acc);

  const int lane = tid & 63;
  const int w = tid >> 6;
  const int wm = (w >> 1) * 64, wn = (w & 1) * 64;
  bf16* dst = (n0 < 1024) ? q : k;
#pragma unroll
  for (int mi = 0; mi < 4; ++mi) {
    const int tB = m0 + wm + mi * 16 + ((lane >> 4) << 2);
#pragma unroll
    for (int ni = 0; ni < 4; ++ni) {
      const int n = n0 + wn + ni * 16 + (lane & 15);
      const float bb = bias[n];
      const int nl = n & 1023;
      f32x4 a = acc[mi][ni];
#pragma unroll
      for (int r2 = 0; r2 < 4; ++r2) dst[(size_t)(tB + r2) * NFD + nl] = (bf16)(a[r2] + bb);
    }
  }
}

// ---- K2 (fused): blocks [0,256) = v-projection (writes vT); blocks [256,784) =
//      masked exp-scores (triangular XCD grid, R10). Independent halves: scores
//      read q,k (prior kernel); v reads xb/WbT (no overlap with P now).
//      Co-dispatch raises residency to ~3 blocks/CU and lets v-blocks' MFMA
//      fill score-blocks' barrier-drain stalls (m114 overlap). ----
__global__ __launch_bounds__(256, 2) void k_fused(const bf16* __restrict__ xb, const bf16* __restrict__ wbt,
                                                  const float* __restrict__ bias, bf16* __restrict__ vT,
                                                  const bf16* __restrict__ q, const bf16* __restrict__ kk,
                                                  bf16* __restrict__ P, float* __restrict__ l,
                                                  const int* __restrict__ npadd_p) {
  __shared__ bf16 As[2 * 128 * 32], Bs[2 * 128 * 32];
  const int tid = threadIdx.x;
  if (blockIdx.x < 256) {
    // ---- v-projection: v = xb @ Wv^T + b, written transposed vT[d][t] ----
    const int id = blockIdx.x;
    const int r = id & 7;
    const int s = id >> 3;           // 0..31
    const int it = 4 * r + (s & 3);  // 0..31
    const int jt = 16 + (s >> 2);    // 16..23
    const int m0 = it * 128;
    const int n0 = jt * 128;
    f32x4 acc[4][4];
#pragma unroll
    for (int i = 0; i < 4; ++i)
#pragma unroll
      for (int j = 0; j < 4; ++j) acc[i][j] = (f32x4){0.f, 0.f, 0.f, 0.f};

    gemm_core(xb + (size_t)m0 * CC, wbt + (size_t)n0 * CC, CC, CC, CC / 32, As, Bs, tid, acc);

    const int lane = tid & 63;
    const int w = tid >> 6;
    const int wm = (w >> 1) * 64, wn = (w & 1) * 64;
#pragma unroll
    for (int mi = 0; mi < 4; ++mi) {
      const int tB = m0 + wm + mi * 16 + ((lane >> 4) << 2);
#pragma unroll
      for (int ni = 0; ni < 4; ++ni) {
        const int n = n0 + wn + ni * 16 + (lane & 15);
        const float bb = bias[n];
        f32x4 a = acc[mi][ni];
        bf16x4 pv;
#pragma unroll
        for (int r2 = 0; r2 < 4; ++r2) pv[r2] = (bf16)(a[r2] + bb);
        *(bf16x4*)(vT + (size_t)(n - 2048) * TT + tB) = pv;
      }
    }
    return;
  }
  // ---- scores: P' = exp(mask(q @ k^T / 32)); row sums l via atomicAdd ----
  const int id = blockIdx.x - 256;
  const int lin = (id & 7) * 66 + (id >> 3);
  int band, rem;
  if (lin < 228)      { band = 0; rem = lin; }
  else if (lin < 392) { band = 1; rem = lin - 228; }
  else if (lin < 492) { band = 2; rem = lin - 392; }
  else                { band = 3; rem = lin - 492; }
  int it, jt;
  if (rem < 28) {
    int itp = (int)((sqrtf(8.0f * (float)rem + 1.0f) - 1.0f) * 0.5f);
    while ((itp + 1) * (itp + 2) / 2 <= rem) ++itp;
    while (itp * (itp + 1) / 2 > rem) --itp;
    it = band * 8 + itp;
    jt = band * 8 + (rem - itp * (itp + 1) / 2);
  } else {
    const int rem2 = rem - 28;
    it = band * 8 + 7 + (rem2 >> 3);
    jt = band * 8 + (rem2 & 7);
  }
  const int np = *npadd_p;
  const int jt0 = np >> 7;
  if (jt < jt0) return;

  f32x4 acc[4][4];
#pragma unroll
  for (int i = 0; i < 4; ++i)
#pragma unroll
    for (int j = 0; j < 4; ++j) acc[i][j] = (f32x4){0.f, 0.f, 0.f, 0.f};

  gemm_core(q + (size_t)it * 128 * CC, kk + (size_t)jt * 128 * CC, CC, CC, CC / 32, As, Bs, tid, acc);

  const int lane = tid & 63;
  const int w = tid >> 6;
  const int wm = (w >> 1) * 64, wn = (w & 1) * 64;
  const float scale = 0.03125f;  // 1/sqrt(1024)
#pragma unroll
  for (int mi = 0; mi < 4; ++mi) {
    const int iB = it * 128 + wm + mi * 16 + ((lane >> 4) << 2);
    float rs[4] = {0.f, 0.f, 0.f, 0.f};
#pragma unroll
    for (int ni = 0; ni < 4; ++ni) {
      const int j = jt * 128 + wn + ni * 16 + (lane & 15);
      f32x4 a = acc[mi][ni];
#pragma unroll
      for (int r = 0; r < 4; ++r) {
        const int i = iB + r;
        float p = 0.f;
        if (j <= i && j >= np && i >= np) p = __expf(a[r] * scale);
        const bf16 pb = (bf16)p;
        P[(size_t)i * TT + j] = pb;
        rs[r] += (float)pb;
      }
    }
#pragma unroll
    for (int r = 0; r < 4; ++r) {
      float v = rs[r];
      v += __shfl_xor(v, 1);
      v += __shfl_xor(v, 2);
      v += __shfl_xor(v, 4);
      v += __shfl_xor(v, 8);
      if ((lane & 15) == 0) atomicAdd(&l[iB + r], v);
    }
  }
}

// ---- K3a: 4-way split-K PV, no atomics, XCD sibling co-location (R12). ----
__global__ __launch_bounds__(256, 2) void k_pvc(const bf16* __restrict__ P, const bf16* __restrict__ vT,
                                                bf16* __restrict__ part0, bf16* __restrict__ part1,
                                                bf16* __restrict__ part2,
                                                const float* __restrict__ l, float* __restrict__ y,
                                                const int* __restrict__ npadd_p) {
  const int id = blockIdx.x;          // 0..1023
  const int kgrp = id >> 3;           // 0..127
  const int d0 = (kgrp & 7) * 128;    // d0 index varies within the sibling window
  const int p = (id & 7) + 8 * (kgrp >> 3);  // pair 0..127, id%8 == p%8 -> same XCD
  const int it = p >> 2;              // 0..31
  const int c = p & 3;                // 0..3
  const int np = *npadd_p;
  const int jt0 = np >> 7;
  const int lo = (c == 0) ? 0 : (c == 1 ? 9 : (c == 2 ? 17 : 25));
  const int hi = (c == 0) ? 9 : (c == 1 ? 17 : (c == 2 ? 25 : 32));
  const int jlo = max(lo, jt0);
  const int jhi = min(hi, it + 1);
  if (jlo >= jhi) return;

  __shared__ bf16 As[2 * 128 * 32], Bs[2 * 128 * 32];
  const int tid = threadIdx.x;
  f32x4 acc[4][4];
#pragma unroll
  for (int i = 0; i < 4; ++i)
#pragma unroll
    for (int j = 0; j < 4; ++j) acc[i][j] = (f32x4){0.f, 0.f, 0.f, 0.f};

  gemm_core(P + (size_t)it * 128 * TT + (size_t)jlo * 128,
            vT + (size_t)d0 * TT + (size_t)jlo * 128,
            TT, TT, (jhi - jlo) * 4, As, Bs, tid, acc);

  const int lane = tid & 63;
  const int w = tid >> 6;
  const int wm = (w >> 1) * 64, wn = (w & 1) * 64;
  const bool sole = (jlo == jt0) && (jhi == it + 1);
  if (sole) {
#pragma unroll
    for (int mi = 0; mi < 4; ++mi) {
      const int iB = it * 128 + wm + mi * 16 + ((lane >> 4) << 2);
      float inv4[4];
#pragma unroll
      for (int r = 0; r < 4; ++r) {
        const int i = iB + r;
        inv4[r] = (i >= np) ? (1.0f / l[i]) : 0.0f;
      }
#pragma unroll
      for (int ni = 0; ni < 4; ++ni) {
        const int d = d0 + wn + ni * 16 + (lane & 15);
        f32x4 a = acc[mi][ni];
#pragma unroll
        for (int r = 0; r < 4; ++r)
          y[(size_t)(iB + r) * NFD + d] = a[r] * inv4[r];
      }
    }
  } else if (c == 3) {
#pragma unroll
    for (int mi = 0; mi < 4; ++mi) {
      const int iB = it * 128 + wm + mi * 16 + ((lane >> 4) << 2);
#pragma unroll
      for (int ni = 0; ni < 4; ++ni) {
        const int d = d0 + wn + ni * 16 + (lane & 15);
        f32x4 a = acc[mi][ni];
#pragma unroll
        for (int r = 0; r < 4; ++r)
          y[(size_t)(iB + r) * NFD + d] = a[r];
      }
    }
  } else {
    bf16* __restrict__ part = (c == 0) ? part0 : (c == 1 ? part1 : part2);
    const int base = (c == 2) ? (PB2 * NFD) : (PB0 * NFD);
#pragma unroll
    for (int mi = 0; mi < 4; ++mi) {
      const int iB = it * 128 + wm + mi * 16 + ((lane >> 4) << 2);
#pragma unroll
      for (int ni = 0; ni < 4; ++ni) {
        const int d = d0 + wn + ni * 16 + (lane & 15);
        f32x4 a = acc[mi][ni];
#pragma unroll
        for (int r = 0; r < 4; ++r)
          part[(size_t)(iB + r) * NFD + d - base] = (bf16)a[r];
      }
    }
  }
}

// ---- K3b: finalize multi-chunk rows: y = (sum of active partials [+ y fp32]) / l. ----
__global__ __launch_bounds__(256) void k_norm(const bf16* __restrict__ part0, const bf16* __restrict__ part1,
                                              const bf16* __restrict__ part2,
                                              const float* __restrict__ l, float* __restrict__ y,
                                              const int* __restrict__ npadd_p) {
  const int idx = (blockIdx.x * 256 + threadIdx.x) * 8;
  const int i = idx >> 10;  // / NFD
  const int np = *npadd_p;
  if (i < np) {
    f32x4 z = (f32x4){0.f, 0.f, 0.f, 0.f};
    *(f32x4*)(y + idx) = z;
    *(f32x4*)(y + idx + 4) = z;
    return;
  }
  const int jt0 = np >> 7;
  const int it = i >> 7;
  const int ip1 = it + 1;
  const bool a0 = (max(0, jt0)  < min(9, ip1));
  const bool a1 = (max(9, jt0)  < min(17, ip1));
  const bool a2 = (max(17, jt0) < min(25, ip1));
  const bool a3 = (max(25, jt0) < min(32, ip1));
  const int cnt = (int)a0 + (int)a1 + (int)a2 + (int)a3;
  if (cnt <= 1) return;  // sole-writer row: y already final
  float s[8] = {0.f, 0.f, 0.f, 0.f, 0.f, 0.f, 0.f, 0.f};
  if (a0) {
    bf16x8 a = *(const bf16x8*)(part0 + idx - PB0 * NFD);
#pragma unroll
    for (int j = 0; j < 8; ++j) s[j] += (float)a[j];
  }
  if (a1) {
    bf16x8 a = *(const bf16x8*)(part1 + idx - PB0 * NFD);
#pragma unroll
    for (int j = 0; j < 8; ++j) s[j] += (float)a[j];
  }
  if (a2) {
    bf16x8 a = *(const bf16x8*)(part2 + idx - PB2 * NFD);
#pragma unroll
    for (int j = 0; j < 8; ++j) s[j] += (float)a[j];
  }
  if (a3) {
    f32x4 a = *(const f32x4*)(y + idx);
    f32x4 b = *(const f32x4*)(y + idx + 4);
#pragma unroll
    for (int j = 0; j < 4; ++j) { s[j] += a[j]; s[4 + j] += b[j]; }
  }
  const float inv = 1.0f / l[i];
  f32x4 o0, o1;
#pragma unroll
  for (int j = 0; j < 4; ++j) { o0[j] = s[j] * inv; o1[j] = s[4 + j] * inv; }
  *(f32x4*)(y + idx) = o0;
  *(f32x4*)(y + idx + 4) = o1;
}

extern "C" void kernel_launch(void* const* d_in, const int* in_sizes, int n_in,
                              void* d_out, int out_size, void* d_ws, size_t ws_size,
                              hipStream_t stream) {
  const float* x = (const float*)d_in[0];
  const float* W = (const float*)d_in[1];
  const float* b = (const float*)d_in[2];
  const int* npadd = (const int*)d_in[3];
  float* y = (float*)d_out;

  char* ws = (char*)d_ws;
  const size_t MB = 1u << 20;
  bf16* q  = (bf16*)(ws + 0 * MB);          // 8 MB  [T][C]   (dead after k_fused)
  bf16* kk = (bf16*)(ws + 8 * MB);          // 8 MB  [T][C]   (dead after k_fused)
  // compact PV partials overlay q/kk (15.25 MB total <= 16 MB):
  bf16* part0 = (bf16*)(ws + 0 * MB);                        // rows [1152,4096)
  bf16* part1 = (bf16*)(ws + (size_t)(TT - PB0) * NFD * 2);  // rows [1152,4096)
  bf16* part2 = (bf16*)(ws + (size_t)2 * (TT - PB0) * NFD * 2);  // rows [2176,4096)
  bf16* vT = (bf16*)(ws + 16 * MB);         // 8 MB  [D][T]
  float* l = (float*)(ws + 24 * MB);        // 16 KB
  bf16* P  = (bf16*)(ws + 24 * MB + 65536); // 32 MB [T][T]
  // xb/WbT moved OUT of the P overlay: k_fused's v-blocks read xb/WbT while
  // its score-blocks write P — they must not alias (ws is 256 MB, plenty).
  bf16* xb  = (bf16*)(ws + 60 * MB);        // 8 MB [T][C]
  bf16* WbT = (bf16*)(ws + 68 * MB);        // 6 MB [3N][C]

  // K0: convert x + transpose/convert W + zero l (merged)
  k_prep<<<dim3(2048 + 768 + 1), 256, 0, stream>>>(x, xb, W, WbT, l);
  // K1: q,k projection only (512 blocks, XCD-chunked)
  k_qkv_qk<<<dim3(512), 256, 0, stream>>>(xb, WbT, b, q, kk);
  // K2: fused v-projection (256 blocks) + masked exp-scores (528 blocks)
  k_fused<<<dim3(256 + 528), 256, 0, stream>>>(xb, WbT, b, vT, q, kk, P, l, npadd);
  // K3: 4-way split-K PV, XCD sibling co-location for P-stripe L2 reuse
  k_pvc<<<dim3(1024), 256, 0, stream>>>(P, vT, part0, part1, part2, l, y, npadd);
  // K3b: finalize multi-chunk rows + zero pad rows
  k_norm<<<dim3((TT * NFD) / (256 * 8)), 256, 0, stream>>>(part0, part1, part2, l, y, npadd);
}

// Round 17
// 117.037 us; speedup vs baseline: 1.0258x; 1.0258x over previous
//
#include <hip/hip_runtime.h>
#include <hip/hip_bf16.h>
#include <stdint.h>
#include <stddef.h>

#define TT 4096
#define CC 1024
#define NFD 1024
#define N3 3072
// k_pvc 4-way split-K fixed j-tile boundaries: [0,9) [9,17) [17,25) [25,32)
#define PB0 1152   // first row using part0/part1 (it>=9)
#define PB2 2176   // first row using part2 (it>=17)
#define PB3 3200   // first row using part3 (it>=25)

typedef __bf16 bf16;
typedef __bf16 bf16x8 __attribute__((ext_vector_type(8)));
typedef __bf16 bf16x4 __attribute__((ext_vector_type(4)));
typedef float f32x4 __attribute__((ext_vector_type(4)));

typedef const __attribute__((address_space(1))) unsigned char gl_u8;
typedef __attribute__((address_space(3))) unsigned char lds_u8;

__device__ __forceinline__ void glds16(const void* g, void* l) {
  __builtin_amdgcn_global_load_lds((gl_u8*)g, (lds_u8*)l, 16, 0, 0);
}

// Stage a 128x32 bf16 tile (row-major, ld in elements) into linear LDS [128][32].
__device__ __forceinline__ void stage128x32(const bf16* __restrict__ src, int ld, bf16* lds, int tid) {
  const int lane = tid & 63;
  const int w = tid >> 6;
#pragma unroll
  for (int p = 0; p < 2; ++p) {
    const int lbyte = w * 2048 + p * 1024;              // wave-uniform LDS base (bytes)
    const int row = (lbyte >> 6) + (lane >> 2);         // this lane's 16B lands at row, k8
    const int kel = (lane & 3) << 3;
    glds16(src + row * ld + kel, (char*)lds + lbyte);
  }
}

// ---------- R6 core (best measured across 7 schedule/fusion experiments):
// 128x128, BK=32, 2-buffer, 1 barrier/step. ----------
__device__ __forceinline__ void gemm_core(const bf16* __restrict__ A, const bf16* __restrict__ B,
                                          int lda, int ldb, int ksteps,
                                          bf16* As, bf16* Bs, int tid, f32x4 (&acc)[4][4]) {
  const int lane = tid & 63;
  const int w = tid >> 6;
  const int wm = (w >> 1) * 64;
  const int wn = (w & 1) * 64;
  const int lrow = lane & 15;
  const int lko = (lane >> 4) * 8;
  stage128x32(A, lda, As, tid);
  stage128x32(B, ldb, Bs, tid);
  __syncthreads();
  for (int ks = 0; ks < ksteps; ++ks) {
    const bf16* Ac = As + (ks & 1) * 4096;
    const bf16* Bc = Bs + (ks & 1) * 4096;
    if (ks + 1 < ksteps) {
      stage128x32(A + (ks + 1) * 32, lda, As + ((ks + 1) & 1) * 4096, tid);
      stage128x32(B + (ks + 1) * 32, ldb, Bs + ((ks + 1) & 1) * 4096, tid);
    }
    bf16x8 af[4], bfr[4];
#pragma unroll
    for (int i = 0; i < 4; ++i)
      af[i] = *(const bf16x8*)(Ac + (wm + i * 16 + lrow) * 32 + lko);
#pragma unroll
    for (int i = 0; i < 4; ++i)
      bfr[i] = *(const bf16x8*)(Bc + (wn + i * 16 + lrow) * 32 + lko);
#pragma unroll
    for (int mi = 0; mi < 4; ++mi)
#pragma unroll
      for (int ni = 0; ni < 4; ++ni)
        acc[mi][ni] = __builtin_amdgcn_mfma_f32_16x16x32_bf16(af[mi], bfr[ni], acc[mi][ni], 0, 0, 0);
    __syncthreads();
  }
}

// ---- K0: merged prep. [0,2048): x cvt. [2048,2816): W transpose. 2816: zero l. ----
__global__ __launch_bounds__(256) void k_prep(const float* __restrict__ x, bf16* __restrict__ xb,
                                              const float* __restrict__ Wsrc, bf16* __restrict__ WbT,
                                              float* __restrict__ l) {
  __shared__ float Ls[64][65];
  const int tid = threadIdx.x;
  if (blockIdx.x < 2048) {
    int idx = (blockIdx.x * 256 + tid) * 8;
    f32x4 a = *(const f32x4*)(x + idx);
    f32x4 b = *(const f32x4*)(x + idx + 4);
    bf16x8 o;
#pragma unroll
    for (int j = 0; j < 4; ++j) { o[j] = (bf16)a[j]; o[4 + j] = (bf16)b[j]; }
    *(bf16x8*)(xb + idx) = o;
    return;
  }
  if (blockIdx.x == 2048 + 768) {  // zero the l accumulator (TT floats)
    f32x4 z = (f32x4){0.f, 0.f, 0.f, 0.f};
#pragma unroll
    for (int qq = 0; qq < 4; ++qq)
      *(f32x4*)(l + (qq * 256 + tid) * 4) = z;
    return;
  }
  const int bid = blockIdx.x - 2048;
  const int n0 = (bid % 48) * 64;
  const int c0 = (bid / 48) * 64;
#pragma unroll
  for (int qq = 0; qq < 4; ++qq) {
    int lin = qq * 1024 + tid * 4;
    int r = lin >> 6, cc = lin & 63;
    f32x4 v = *(const f32x4*)(Wsrc + (size_t)(c0 + r) * N3 + n0 + cc);
#pragma unroll
    for (int j = 0; j < 4; ++j) Ls[r][cc + j] = v[j];
  }
  __syncthreads();
#pragma unroll
  for (int qq = 0; qq < 4; ++qq) {
    int lin = qq * 1024 + tid * 4;
    int nr = lin >> 6, cc = lin & 63;
    bf16x4 o;
#pragma unroll
    for (int j = 0; j < 4; ++j) o[j] = (bf16)Ls[cc + j][nr];
    *(bf16x4*)(WbT + (size_t)(n0 + nr) * CC + c0 + cc) = o;
  }
}

// ---- K1: qkv = xb @ WbT^T + b. 1D XCD-chunked grid (R13): XCD r owns 4 it-rows
//      x 24 jt. Writes q,k natural [t][c] and v transposed [d][t]. ----
__global__ __launch_bounds__(256, 2) void k_qkv(const bf16* __restrict__ xb, const bf16* __restrict__ wbt,
                                                const float* __restrict__ bias,
                                                bf16* __restrict__ q, bf16* __restrict__ k,
                                                bf16* __restrict__ vT) {
  __shared__ bf16 As[2 * 128 * 32], Bs[2 * 128 * 32];
  const int tid = threadIdx.x;
  const int id = blockIdx.x;         // 0..767
  const int r = id & 7;              // XCD (round-robin heuristic, m09)
  const int s = id >> 3;             // 0..95 within XCD
  const int it = 4 * r + (s & 3);    // 0..31
  const int jt = s >> 2;             // 0..23
  const int m0 = it * 128;
  const int n0 = jt * 128;
  f32x4 acc[4][4];
#pragma unroll
  for (int i = 0; i < 4; ++i)
#pragma unroll
    for (int j = 0; j < 4; ++j) acc[i][j] = (f32x4){0.f, 0.f, 0.f, 0.f};

  gemm_core(xb + (size_t)m0 * CC, wbt + (size_t)n0 * CC, CC, CC, CC / 32, As, Bs, tid, acc);

  const int lane = tid & 63;
  const int w = tid >> 6;
  const int wm = (w >> 1) * 64, wn = (w & 1) * 64;
  const int seg = n0 >> 10;  // 0:q 1:k 2:v
#pragma unroll
  for (int mi = 0; mi < 4; ++mi) {
    const int tB = m0 + wm + mi * 16 + ((lane >> 4) << 2);
#pragma unroll
    for (int ni = 0; ni < 4; ++ni) {
      const int n = n0 + wn + ni * 16 + (lane & 15);
      const float bb = bias[n];
      f32x4 a = acc[mi][ni];
      if (seg == 2) {
        bf16x4 pv;
#pragma unroll
        for (int r2 = 0; r2 < 4; ++r2) pv[r2] = (bf16)(a[r2] + bb);
        *(bf16x4*)(vT + (size_t)(n - 2048) * TT + tB) = pv;  // vT[d][t]
      } else {
        bf16* dst = (seg == 0) ? q : k;
        const int nl = n & 1023;
#pragma unroll
        for (int r2 = 0; r2 < 4; ++r2) dst[(size_t)(tB + r2) * NFD + nl] = (bf16)(a[r2] + bb);
      }
    }
  }
}

// ---- K2: P' = exp(mask(q @ k^T / 32)) as bf16; row sums l via atomicAdd.
//      Compact triangular XCD-chunked grid (R10), R6 core. ----
__global__ __launch_bounds__(256, 2) void k_scores(const bf16* __restrict__ q, const bf16* __restrict__ kk,
                                                   bf16* __restrict__ P, float* __restrict__ l,
                                                   const int* __restrict__ npadd_p) {
  const int id = blockIdx.x;
  const int lin = (id & 7) * 66 + (id >> 3);
  int band, rem;
  if (lin < 228)      { band = 0; rem = lin; }
  else if (lin < 392) { band = 1; rem = lin - 228; }
  else if (lin < 492) { band = 2; rem = lin - 392; }
  else                { band = 3; rem = lin - 492; }
  int it, jt;
  if (rem < 28) {
    int itp = (int)((sqrtf(8.0f * (float)rem + 1.0f) - 1.0f) * 0.5f);
    while ((itp + 1) * (itp + 2) / 2 <= rem) ++itp;
    while (itp * (itp + 1) / 2 > rem) --itp;
    it = band * 8 + itp;
    jt = band * 8 + (rem - itp * (itp + 1) / 2);
  } else {
    const int rem2 = rem - 28;
    it = band * 8 + 7 + (rem2 >> 3);
    jt = band * 8 + (rem2 & 7);
  }
  const int np = *npadd_p;
  const int jt0 = np >> 7;
  if (jt < jt0) return;

  __shared__ bf16 As[2 * 128 * 32], Bs[2 * 128 * 32];
  const int tid = threadIdx.x;
  f32x4 acc[4][4];
#pragma unroll
  for (int i = 0; i < 4; ++i)
#pragma unroll
    for (int j = 0; j < 4; ++j) acc[i][j] = (f32x4){0.f, 0.f, 0.f, 0.f};

  gemm_core(q + (size_t)it * 128 * CC, kk + (size_t)jt * 128 * CC, CC, CC, CC / 32, As, Bs, tid, acc);

  const int lane = tid & 63;
  const int w = tid >> 6;
  const int wm = (w >> 1) * 64, wn = (w & 1) * 64;
  const float scale = 0.03125f;  // 1/sqrt(1024)
#pragma unroll
  for (int mi = 0; mi < 4; ++mi) {
    const int iB = it * 128 + wm + mi * 16 + ((lane >> 4) << 2);
    float rs[4] = {0.f, 0.f, 0.f, 0.f};
#pragma unroll
    for (int ni = 0; ni < 4; ++ni) {
      const int j = jt * 128 + wn + ni * 16 + (lane & 15);
      f32x4 a = acc[mi][ni];
#pragma unroll
      for (int r = 0; r < 4; ++r) {
        const int i = iB + r;
        float p = 0.f;
        if (j <= i && j >= np && i >= np) p = __expf(a[r] * scale);
        const bf16 pb = (bf16)p;
        P[(size_t)i * TT + j] = pb;
        rs[r] += (float)pb;
      }
    }
#pragma unroll
    for (int r = 0; r < 4; ++r) {
      float v = rs[r];
      v += __shfl_xor(v, 1);
      v += __shfl_xor(v, 2);
      v += __shfl_xor(v, 4);
      v += __shfl_xor(v, 8);
      if ((lane & 15) == 0) atomicAdd(&l[iB + r], v);
    }
  }
}

// ---- K3a: 4-way split-K PV, no atomics, XCD sibling co-location (R12).
//      All non-sole chunks write compact bf16 partials (chunk 3 now too). ----
__global__ __launch_bounds__(256, 2) void k_pvc(const bf16* __restrict__ P, const bf16* __restrict__ vT,
                                                bf16* __restrict__ part0, bf16* __restrict__ part1,
                                                bf16* __restrict__ part2, bf16* __restrict__ part3,
                                                const float* __restrict__ l, float* __restrict__ y,
                                                const int* __restrict__ npadd_p) {
  const int id = blockIdx.x;          // 0..1023
  const int kgrp = id >> 3;           // 0..127
  const int d0 = (kgrp & 7) * 128;    // d0 index varies within the sibling window
  const int p = (id & 7) + 8 * (kgrp >> 3);  // pair 0..127, id%8 == p%8 -> same XCD
  const int it = p >> 2;              // 0..31
  const int c = p & 3;                // 0..3
  const int np = *npadd_p;
  const int jt0 = np >> 7;
  const int lo = (c == 0) ? 0 : (c == 1 ? 9 : (c == 2 ? 17 : 25));
  const int hi = (c == 0) ? 9 : (c == 1 ? 17 : (c == 2 ? 25 : 32));
  const int jlo = max(lo, jt0);
  const int jhi = min(hi, it + 1);
  if (jlo >= jhi) return;

  __shared__ bf16 As[2 * 128 * 32], Bs[2 * 128 * 32];
  const int tid = threadIdx.x;
  f32x4 acc[4][4];
#pragma unroll
  for (int i = 0; i < 4; ++i)
#pragma unroll
    for (int j = 0; j < 4; ++j) acc[i][j] = (f32x4){0.f, 0.f, 0.f, 0.f};

  gemm_core(P + (size_t)it * 128 * TT + (size_t)jlo * 128,
            vT + (size_t)d0 * TT + (size_t)jlo * 128,
            TT, TT, (jhi - jlo) * 4, As, Bs, tid, acc);

  const int lane = tid & 63;
  const int w = tid >> 6;
  const int wm = (w >> 1) * 64, wn = (w & 1) * 64;
  const bool sole = (jlo == jt0) && (jhi == it + 1);
  if (sole) {
#pragma unroll
    for (int mi = 0; mi < 4; ++mi) {
      const int iB = it * 128 + wm + mi * 16 + ((lane >> 4) << 2);
      float inv4[4];
#pragma unroll
      for (int r = 0; r < 4; ++r) {
        const int i = iB + r;
        inv4[r] = (i >= np) ? (1.0f / l[i]) : 0.0f;
      }
#pragma unroll
      for (int ni = 0; ni < 4; ++ni) {
        const int d = d0 + wn + ni * 16 + (lane & 15);
        f32x4 a = acc[mi][ni];
#pragma unroll
        for (int r = 0; r < 4; ++r)
          y[(size_t)(iB + r) * NFD + d] = a[r] * inv4[r];
      }
    }
  } else {
    bf16* __restrict__ part = (c == 0) ? part0 : (c == 1 ? part1 : (c == 2 ? part2 : part3));
    const int base = (c == 3) ? (PB3 * NFD) : ((c == 2) ? (PB2 * NFD) : (PB0 * NFD));
#pragma unroll
    for (int mi = 0; mi < 4; ++mi) {
      const int iB = it * 128 + wm + mi * 16 + ((lane >> 4) << 2);
#pragma unroll
      for (int ni = 0; ni < 4; ++ni) {
        const int d = d0 + wn + ni * 16 + (lane & 15);
        f32x4 a = acc[mi][ni];
#pragma unroll
        for (int r = 0; r < 4; ++r)
          part[(size_t)(iB + r) * NFD + d - base] = (bf16)a[r];
      }
    }
  }
}

// ---- K3b: finalize multi-chunk rows: y = (sum of active bf16 partials) / l. ----
__global__ __launch_bounds__(256) void k_norm(const bf16* __restrict__ part0, const bf16* __restrict__ part1,
                                              const bf16* __restrict__ part2, const bf16* __restrict__ part3,
                                              const float* __restrict__ l, float* __restrict__ y,
                                              const int* __restrict__ npadd_p) {
  const int idx = (blockIdx.x * 256 + threadIdx.x) * 8;
  const int i = idx >> 10;  // / NFD
  const int np = *npadd_p;
  if (i < np) {
    f32x4 z = (f32x4){0.f, 0.f, 0.f, 0.f};
    *(f32x4*)(y + idx) = z;
    *(f32x4*)(y + idx + 4) = z;
    return;
  }
  const int jt0 = np >> 7;
  const int it = i >> 7;
  const int ip1 = it + 1;
  const bool a0 = (max(0, jt0)  < min(9, ip1));
  const bool a1 = (max(9, jt0)  < min(17, ip1));
  const bool a2 = (max(17, jt0) < min(25, ip1));
  const bool a3 = (max(25, jt0) < min(32, ip1));
  const int cnt = (int)a0 + (int)a1 + (int)a2 + (int)a3;
  if (cnt <= 1) return;  // sole-writer row: y already final
  float s[8] = {0.f, 0.f, 0.f, 0.f, 0.f, 0.f, 0.f, 0.f};
  if (a0) {
    bf16x8 a = *(const bf16x8*)(part0 + idx - PB0 * NFD);
#pragma unroll
    for (int j = 0; j < 8; ++j) s[j] += (float)a[j];
  }
  if (a1) {
    bf16x8 a = *(const bf16x8*)(part1 + idx - PB0 * NFD);
#pragma unroll
    for (int j = 0; j < 8; ++j) s[j] += (float)a[j];
  }
  if (a2) {
    bf16x8 a = *(const bf16x8*)(part2 + idx - PB2 * NFD);
#pragma unroll
    for (int j = 0; j < 8; ++j) s[j] += (float)a[j];
  }
  if (a3) {
    bf16x8 a = *(const bf16x8*)(part3 + idx - PB3 * NFD);
#pragma unroll
    for (int j = 0; j < 8; ++j) s[j] += (float)a[j];
  }
  const float inv = 1.0f / l[i];
  f32x4 o0, o1;
#pragma unroll
  for (int j = 0; j < 4; ++j) { o0[j] = s[j] * inv; o1[j] = s[4 + j] * inv; }
  *(f32x4*)(y + idx) = o0;
  *(f32x4*)(y + idx + 4) = o1;
}

extern "C" void kernel_launch(void* const* d_in, const int* in_sizes, int n_in,
                              void* d_out, int out_size, void* d_ws, size_t ws_size,
                              hipStream_t stream) {
  const float* x = (const float*)d_in[0];
  const float* W = (const float*)d_in[1];
  const float* b = (const float*)d_in[2];
  const int* npadd = (const int*)d_in[3];
  float* y = (float*)d_out;

  char* ws = (char*)d_ws;
  const size_t MB = 1u << 20;
  bf16* q  = (bf16*)(ws + 0 * MB);          // 8 MB  [T][C]   (dead after k_scores)
  bf16* kk = (bf16*)(ws + 8 * MB);          // 8 MB  [T][C]   (dead after k_scores)
  // compact PV partials overlay q/kk (15.25 MB <= 16 MB):
  bf16* part0 = (bf16*)(ws + 0 * MB);                            // rows [1152,4096)
  bf16* part1 = (bf16*)(ws + (size_t)(TT - PB0) * NFD * 2);      // rows [1152,4096)
  bf16* part2 = (bf16*)(ws + (size_t)2 * (TT - PB0) * NFD * 2);  // rows [2176,4096)
  bf16* vT = (bf16*)(ws + 16 * MB);         // 8 MB  [D][T]
  float* l = (float*)(ws + 24 * MB);        // 16 KB
  bf16* P  = (bf16*)(ws + 24 * MB + 65536); // 32 MB [T][T]
  bf16* xb = P;                              // overlap: dead before K2 writes P
  bf16* WbT = (bf16*)((char*)P + 8 * MB);    // 6 MB, also dead before K2
  bf16* part3 = (bf16*)(ws + 60 * MB);      // 1.75 MB, rows [3200,4096) (free space)

  // K0: convert x + transpose/convert W + zero l (merged)
  k_prep<<<dim3(2048 + 768 + 1), 256, 0, stream>>>(x, xb, W, WbT, l);
  // K1: QKV projection (1D XCD-chunked grid)
  k_qkv<<<dim3(768), 256, 0, stream>>>(xb, WbT, b, q, kk, vT);
  // K2: masked exp-scores + row sums (triangular XCD grid, R6 core)
  k_scores<<<dim3(528), 256, 0, stream>>>(q, kk, P, l, npadd);
  // K3: 4-way split-K PV, XCD sibling co-location; all partials bf16 now
  k_pvc<<<dim3(1024), 256, 0, stream>>>(P, vT, part0, part1, part2, part3, l, y, npadd);
  // K3b: finalize multi-chunk rows + zero pad rows
  k_norm<<<dim3((TT * NFD) / (256 * 8)), 256, 0, stream>>>(part0, part1, part2, part3, l, y, npadd);
}